// Round 2
// baseline (19145.451 us; speedup 1.0000x reference)
//
#include <hip/hip_runtime.h>
#include <stdint.h>

// ---------------- problem constants ----------------
#define TSTEPS 512
#define NB     256          // batch
#define DIN    85
#define DPAD   96
#define HID    512
#define ODIM   33
#define OPAD   48
#define TBROWS (TSTEPS*NB)  // 131072
#define NBLK   128          // persistent blocks (<=256 CUs -> guaranteed co-resident)

typedef unsigned int u32;
typedef unsigned short u16;
typedef unsigned long long u64;
typedef __bf16 bf16x8 __attribute__((ext_vector_type(8)));
typedef float  f32x4  __attribute__((ext_vector_type(4)));

__device__ __forceinline__ u16 f2bf(float f) {
  u32 u = __float_as_uint(f);
  return (u16)((u + 0x7FFFu + ((u >> 16) & 1u)) >> 16);   // RNE
}
__device__ __forceinline__ float bf2f(u16 h) {
  return __uint_as_float(((u32)h) << 16);
}
__device__ __forceinline__ bf16x8 bc8(uint4 v) {
  return __builtin_bit_cast(bf16x8, v);
}
__device__ __forceinline__ f32x4 mfma_bf16(bf16x8 a, bf16x8 b, f32x4 c) {
  return __builtin_amdgcn_mfma_f32_16x16x32_bf16(a, b, c, 0, 0, 0);
}
__device__ __forceinline__ float fsigmoid(float x) { return 1.0f / (1.0f + __expf(-x)); }
__device__ __forceinline__ float ftanh(float x)    { return 2.0f / (1.0f + __expf(-2.0f*x)) - 1.0f; }

// agent-scope (LLC-coherent) accesses for cross-block mutable data
__device__ __forceinline__ void st_u32_llc(u32* p, u32 v) {
  __hip_atomic_store(p, v, __ATOMIC_RELAXED, __HIP_MEMORY_SCOPE_AGENT);
}
__device__ __forceinline__ u32 ld_u32_llc(const u32* p) {
  return __hip_atomic_load(p, __ATOMIC_RELAXED, __HIP_MEMORY_SCOPE_AGENT);
}
__device__ __forceinline__ u64 ld_u64_llc(const u64* p) {
  return __hip_atomic_load(p, __ATOMIC_RELAXED, __HIP_MEMORY_SCOPE_AGENT);
}
__device__ __forceinline__ void st_f32_llc(float* p, float v) {
  __hip_atomic_store(p, v, __ATOMIC_RELAXED, __HIP_MEMORY_SCOPE_AGENT);
}
__device__ __forceinline__ float ld_f32_llc(const float* p) {
  return __hip_atomic_load(p, __ATOMIC_RELAXED, __HIP_MEMORY_SCOPE_AGENT);
}

// ---------------- prep: bf16 weight conversions ----------------
__global__ void __launch_bounds__(256) prep_kernel(
    const float* __restrict__ Whr, const float* __restrict__ Whz, const float* __restrict__ Whh,
    const float* __restrict__ Wxr, const float* __restrict__ Wxz, const float* __restrict__ Wxh,
    const float* __restrict__ Wro,
    u16* __restrict__ w_hb, u16* __restrict__ wx_hi, u16* __restrict__ wx_lo,
    u16* __restrict__ w_rob)
{
  int tid = blockIdx.x * blockDim.x + threadIdx.x;
  int np  = gridDim.x * blockDim.x;
  for (int i = tid; i < 3 * HID * HID; i += np) {
    int m = i / (HID * HID), r = i % (HID * HID);
    const float* src = (m == 0) ? Whr : ((m == 1) ? Whz : Whh);
    w_hb[i] = f2bf(src[r]);
  }
  for (int i = tid; i < 3 * HID * DPAD; i += np) {
    int m = i / (HID * DPAD), r = i % (HID * DPAD);
    int row = r / DPAD, k = r % DPAD;
    const float* src = (m == 0) ? Wxr : ((m == 1) ? Wxz : Wxh);
    u16 hi = 0, lo = 0;
    if (k < DIN) {
      float v = src[row * DIN + k];
      hi = f2bf(v);
      lo = f2bf(v - bf2f(hi));
    }
    wx_hi[i] = hi; wx_lo[i] = lo;
  }
  for (int i = tid; i < OPAD * HID; i += np) {
    int row = i / HID, k = i % HID;
    w_rob[i] = (row < ODIM) ? f2bf(Wro[row * HID + k]) : (u16)0;
  }
}

// ---------------- grid barrier (all NBLK blocks resident by construction) ----------------
__device__ __forceinline__ void grid_barrier(u32* flags, int bid, u32 target) {
  __syncthreads();
  if (threadIdx.x == 0)
    __hip_atomic_store(&flags[bid * 32], target, __ATOMIC_RELEASE, __HIP_MEMORY_SCOPE_AGENT);
  if (threadIdx.x < 64) {
    int i0 = threadIdx.x, i1 = threadIdx.x + 64;
    for (;;) {
      u32 a = __hip_atomic_load(&flags[i0 * 32], __ATOMIC_RELAXED, __HIP_MEMORY_SCOPE_AGENT);
      u32 b = __hip_atomic_load(&flags[i1 * 32], __ATOMIC_RELAXED, __HIP_MEMORY_SCOPE_AGENT);
      if (__all(a >= target && b >= target)) break;
      __builtin_amdgcn_s_sleep(2);
    }
  }
  __syncthreads();
  asm volatile("" ::: "memory");
}

// ---------------- persistent recurrence kernel ----------------
__global__ void __launch_bounds__(256, 1) recur_kernel(
    const float* __restrict__ x,  const float* __restrict__ nr,
    const float* __restrict__ nz, const float* __restrict__ nh,
    const float* __restrict__ bhr, const float* __restrict__ bhz, const float* __restrict__ bhh,
    const u16* __restrict__ wx_hi, const u16* __restrict__ wx_lo, const u16* __restrict__ w_hb,
    u32* __restrict__ h_ring, u32* __restrict__ g_pack, float* __restrict__ z_buf,
    u32* __restrict__ flags,
    u16* __restrict__ hs_out,                 // null => inline out (phase C)
    const float* __restrict__ Wro, const float* __restrict__ bro, float* __restrict__ out,
    int do_c)
{
  __shared__ __attribute__((aligned(16))) u16 sAh[2][64][72];
  __shared__ __attribute__((aligned(16))) u16 sAl[2][64][72];
  __shared__ __attribute__((aligned(16))) u16 sXh[64][104];
  __shared__ __attribute__((aligned(16))) u16 sXl[64][104];
  __shared__ float sC[2][33][4];

  const int bid  = blockIdx.x;
  const int tid  = threadIdx.x;
  const int lane = tid & 63;
  const int wave = tid >> 6;

  // phase A geometry: [64b x 32n'] tiles over [256 x 1024] (R cols then Z cols)
  const int btA   = bid >> 5;
  const int ntA   = bid & 31;
  const int isZ   = (ntA >= 16);
  const int ncA   = (isZ ? (ntA - 16) : ntA) * 32;
  const u16*  WA   = w_hb + (size_t)(isZ ? 1 : 0) * HID * HID;
  const u16*  WXAh = wx_hi + (size_t)(isZ ? 1 : 0) * HID * DPAD;
  const u16*  WXAl = wx_lo + (size_t)(isZ ? 1 : 0) * HID * DPAD;
  const float* nA  = isZ ? nz : nr;
  const int mhA = wave >> 1, nhA = wave & 1;      // wave tile [32m x 16n]
  const int colA = ncA + nhA * 16 + (lane & 15);
  const float biasA = (isZ ? bhz : bhr)[colA];

  // phase B geometry: [64b x 16n] tiles over [256 x 512]
  const int btB  = bid >> 5;
  const int ncB  = (bid & 31) * 16;
  const u16*  WH   = w_hb + (size_t)2 * HID * HID;
  const u16*  WXBh = wx_hi + (size_t)2 * HID * DPAD;
  const u16*  WXBl = wx_lo + (size_t)2 * HID * DPAD;
  const int colB = ncB + (lane & 15);
  const float biasB = bhh[colB];

  float h_old[4] = {0.f, 0.f, 0.f, 0.f};

  // zero the k-pad of the x staging buffers once (cols 85..95 never rewritten)
  for (int c = tid; c < 64 * 11; c += 256) {
    int row = c / 11, k = DIN + c % 11;
    sXh[row][k] = 0; sXl[row][k] = 0;
  }
  __syncthreads();

  u64 hv[8];

  for (int t = 1; t <= TSTEPS; ++t) {
    const int row0 = (t - 1) * NB;

    // ---------- phase C (inline out-projection) for step t-1 ----------
    if (do_c && t >= 2) {
      const int tp = t - 1;
      const int q = tid >> 6, idx = tid & 63, r2 = idx >> 5, o = idx & 31;
      const int row = bid * 2 + r2;
      const u64* hp = (const u64*)(h_ring + (size_t)(tp & 1) * NB * HID) + (size_t)row * 256 + q * 64;
      float acc = 0.f;
      #pragma unroll 8
      for (int kk = 0; kk < 64; ++kk) {
        u64 v = ld_u64_llc(&hp[kk]);
        u32 v0 = (u32)v, v1 = (u32)(v >> 32);
        float h0 = bf2f((u16)(v0 >> 16)) + bf2f((u16)(v0 & 0xFFFFu));
        float h1 = bf2f((u16)(v1 >> 16)) + bf2f((u16)(v1 & 0xFFFFu));
        int k = q * 128 + 2 * kk;
        acc += h0 * Wro[(size_t)o * HID + k] + h1 * Wro[(size_t)o * HID + k + 1];
      }
      sC[r2][o][q] = acc;
      if (idx < 2) {   // column 32
        const int rowb = bid * 2 + idx;
        const u64* hp2 = (const u64*)(h_ring + (size_t)(tp & 1) * NB * HID) + (size_t)rowb * 256 + q * 64;
        float a2 = 0.f;
        #pragma unroll 8
        for (int kk = 0; kk < 64; ++kk) {
          u64 v = ld_u64_llc(&hp2[kk]);
          u32 v0 = (u32)v, v1 = (u32)(v >> 32);
          float h0 = bf2f((u16)(v0 >> 16)) + bf2f((u16)(v0 & 0xFFFFu));
          float h1 = bf2f((u16)(v1 >> 16)) + bf2f((u16)(v1 & 0xFFFFu));
          int k = q * 128 + 2 * kk;
          a2 += h0 * Wro[(size_t)32 * HID + k] + h1 * Wro[(size_t)32 * HID + k + 1];
        }
        sC[idx][32][q] = a2;
      }
      __syncthreads();
      if (tid < 66) {
        int rr = tid / 33, oo = tid % 33;
        float s = sC[rr][oo][0] + sC[rr][oo][1] + sC[rr][oo][2] + sC[rr][oo][3] + bro[oo];
        out[(size_t)((tp - 1) * NB + bid * 2 + rr) * ODIM + oo] = s;
      }
      __syncthreads();
    }

    // ================= PHASE A: R and Z =================
    // stage split(x + noise) for this strip
    {
      const size_t xoff = (size_t)(row0 + btA * 64) * DIN;
      for (int c = tid; c < 64 * DIN; c += 256) {
        int row = c / DIN, k = c - row * DIN;
        float v = x[xoff + c] + nA[xoff + c];
        u16 hi = f2bf(v);
        sXh[row][k] = hi;
        sXl[row][k] = f2bf(v - bf2f(hi));
      }
    }
    // stage h chunk 0 (packed hi|lo u32, agent loads)
    const u64* hsrc = (const u64*)(h_ring + (size_t)((t - 1) & 1) * NB * HID);
    {
      #pragma unroll
      for (int i = 0; i < 8; ++i) {
        int c = tid + 256 * i; int row = c >> 5, cp = c & 31;
        hv[i] = ld_u64_llc(&hsrc[(size_t)(btA * 64 + row) * 256 + cp]);
      }
      #pragma unroll
      for (int i = 0; i < 8; ++i) {
        int c = tid + 256 * i; int row = c >> 5, cp = c & 31;
        u32 v0 = (u32)hv[i], v1 = (u32)(hv[i] >> 32);
        ((u32*)&sAh[0][row][0])[cp] = (v0 >> 16) | (v1 & 0xFFFF0000u);
        ((u32*)&sAl[0][row][0])[cp] = (v0 & 0xFFFFu) | (v1 << 16);
      }
    }
    __syncthreads();

    f32x4 accA[2];
    accA[0] = {0.f, 0.f, 0.f, 0.f}; accA[1] = {0.f, 0.f, 0.f, 0.f};

    // x-projection GEMM (K=96)
    #pragma unroll
    for (int ks = 0; ks < 3; ++ks) {
      int kk = ks * 32 + 8 * (lane >> 4);
      bf16x8 wh = bc8(*(const uint4*)&WXAh[(size_t)colA * DPAD + kk]);
      bf16x8 wl = bc8(*(const uint4*)&WXAl[(size_t)colA * DPAD + kk]);
      #pragma unroll
      for (int mf = 0; mf < 2; ++mf) {
        int rowl = mhA * 32 + mf * 16 + (lane & 15);
        bf16x8 xh = bc8(*(const uint4*)&sXh[rowl][kk]);
        bf16x8 xl = bc8(*(const uint4*)&sXl[rowl][kk]);
        accA[mf] = mfma_bf16(xh, wh, accA[mf]);
        accA[mf] = mfma_bf16(xl, wh, accA[mf]);
        accA[mf] = mfma_bf16(xh, wl, accA[mf]);
      }
    }

    // h GEMM (K=512, double-buffered chunks of 64)
    for (int kc = 0; kc < 8; ++kc) {
      int buf = kc & 1;
      if (kc < 7) {
        #pragma unroll
        for (int i = 0; i < 8; ++i) {
          int c = tid + 256 * i; int row = c >> 5, cp = c & 31;
          hv[i] = ld_u64_llc(&hsrc[(size_t)(btA * 64 + row) * 256 + (kc + 1) * 32 + cp]);
        }
      }
      #pragma unroll
      for (int ks = 0; ks < 2; ++ks) {
        int klocal = ks * 32 + 8 * (lane >> 4);
        int kglob  = kc * 64 + klocal;
        bf16x8 bw = bc8(*(const uint4*)&WA[(size_t)colA * HID + kglob]);
        #pragma unroll
        for (int mf = 0; mf < 2; ++mf) {
          int rowl = mhA * 32 + mf * 16 + (lane & 15);
          bf16x8 ah = bc8(*(const uint4*)&sAh[buf][rowl][klocal]);
          bf16x8 al = bc8(*(const uint4*)&sAl[buf][rowl][klocal]);
          accA[mf] = mfma_bf16(ah, bw, accA[mf]);
          accA[mf] = mfma_bf16(al, bw, accA[mf]);
        }
      }
      if (kc < 7) {
        #pragma unroll
        for (int i = 0; i < 8; ++i) {
          int c = tid + 256 * i; int row = c >> 5, cp = c & 31;
          u32 v0 = (u32)hv[i], v1 = (u32)(hv[i] >> 32);
          ((u32*)&sAh[buf ^ 1][row][0])[cp] = (v0 >> 16) | (v1 & 0xFFFF0000u);
          ((u32*)&sAl[buf ^ 1][row][0])[cp] = (v0 & 0xFFFFu) | (v1 << 16);
        }
      }
      __syncthreads();
    }

    // epilogue A
    #pragma unroll
    for (int mf = 0; mf < 2; ++mf)
      #pragma unroll
      for (int r = 0; r < 4; ++r) {
        int b = btA * 64 + mhA * 32 + mf * 16 + (lane >> 4) * 4 + r;
        float val = fsigmoid(accA[mf][r] + biasA);
        if (!isZ) {
          u32 hvp = ld_u32_llc(&h_ring[(size_t)((t - 1) & 1) * NB * HID + (size_t)b * HID + colA]);
          float hcur = bf2f((u16)(hvp >> 16)) + bf2f((u16)(hvp & 0xFFFFu));
          float g = val * hcur;
          u16 gh = f2bf(g);
          u16 gl = f2bf(g - bf2f(gh));
          st_u32_llc(&g_pack[(size_t)b * HID + colA], ((u32)gh << 16) | (u32)gl);
        } else {
          st_f32_llc(&z_buf[(size_t)b * HID + colA], val);
        }
      }

    grid_barrier(flags, bid, (u32)(2 * t - 1));

    // ================= PHASE B: Hh + state update =================
    // stage split(x + h_noise)
    {
      const size_t xoff = (size_t)(row0 + btB * 64) * DIN;
      for (int c = tid; c < 64 * DIN; c += 256) {
        int row = c / DIN, k = c - row * DIN;
        float v = x[xoff + c] + nh[xoff + c];
        u16 hi = f2bf(v);
        sXh[row][k] = hi;
        sXl[row][k] = f2bf(v - bf2f(hi));
      }
    }
    // stage g chunk 0
    const u64* gsrc = (const u64*)g_pack;
    {
      #pragma unroll
      for (int i = 0; i < 8; ++i) {
        int c = tid + 256 * i; int row = c >> 5, cp = c & 31;
        hv[i] = ld_u64_llc(&gsrc[(size_t)(btB * 64 + row) * 256 + cp]);
      }
      #pragma unroll
      for (int i = 0; i < 8; ++i) {
        int c = tid + 256 * i; int row = c >> 5, cp = c & 31;
        u32 v0 = (u32)hv[i], v1 = (u32)(hv[i] >> 32);
        ((u32*)&sAh[0][row][0])[cp] = (v0 >> 16) | (v1 & 0xFFFF0000u);
        ((u32*)&sAl[0][row][0])[cp] = (v0 & 0xFFFFu) | (v1 << 16);
      }
    }
    __syncthreads();

    f32x4 accB = {0.f, 0.f, 0.f, 0.f};

    // x-projection GEMM (K=96), wave tile [16m x 16n]
    #pragma unroll
    for (int ks = 0; ks < 3; ++ks) {
      int kk = ks * 32 + 8 * (lane >> 4);
      bf16x8 wh = bc8(*(const uint4*)&WXBh[(size_t)colB * DPAD + kk]);
      bf16x8 wl = bc8(*(const uint4*)&WXBl[(size_t)colB * DPAD + kk]);
      int rowl = wave * 16 + (lane & 15);
      bf16x8 xh = bc8(*(const uint4*)&sXh[rowl][kk]);
      bf16x8 xl = bc8(*(const uint4*)&sXl[rowl][kk]);
      accB = mfma_bf16(xh, wh, accB);
      accB = mfma_bf16(xl, wh, accB);
      accB = mfma_bf16(xh, wl, accB);
    }

    for (int kc = 0; kc < 8; ++kc) {
      int buf = kc & 1;
      if (kc < 7) {
        #pragma unroll
        for (int i = 0; i < 8; ++i) {
          int c = tid + 256 * i; int row = c >> 5, cp = c & 31;
          hv[i] = ld_u64_llc(&gsrc[(size_t)(btB * 64 + row) * 256 + (kc + 1) * 32 + cp]);
        }
      }
      #pragma unroll
      for (int ks = 0; ks < 2; ++ks) {
        int klocal = ks * 32 + 8 * (lane >> 4);
        int kglob  = kc * 64 + klocal;
        int rowl   = wave * 16 + (lane & 15);
        bf16x8 bw = bc8(*(const uint4*)&WH[(size_t)colB * HID + kglob]);
        bf16x8 ah = bc8(*(const uint4*)&sAh[buf][rowl][klocal]);
        bf16x8 al = bc8(*(const uint4*)&sAl[buf][rowl][klocal]);
        accB = mfma_bf16(ah, bw, accB);
        accB = mfma_bf16(al, bw, accB);
      }
      if (kc < 7) {
        #pragma unroll
        for (int i = 0; i < 8; ++i) {
          int c = tid + 256 * i; int row = c >> 5, cp = c & 31;
          u32 v0 = (u32)hv[i], v1 = (u32)(hv[i] >> 32);
          ((u32*)&sAh[buf ^ 1][row][0])[cp] = (v0 >> 16) | (v1 & 0xFFFF0000u);
          ((u32*)&sAl[buf ^ 1][row][0])[cp] = (v0 & 0xFFFFu) | (v1 << 16);
        }
      }
      __syncthreads();
    }

    // epilogue B
    #pragma unroll
    for (int r = 0; r < 4; ++r) {
      int b = btB * 64 + wave * 16 + (lane >> 4) * 4 + r;
      float hh = ftanh(accB[r] + biasB);
      float z  = ld_f32_llc(&z_buf[(size_t)b * HID + colB]);
      float hn = z * h_old[r] + (1.0f - z) * hh;
      h_old[r] = hn;
      u16 hi = f2bf(hn);
      u16 lo = f2bf(hn - bf2f(hi));
      st_u32_llc(&h_ring[(size_t)(t & 1) * NB * HID + (size_t)b * HID + colB],
                 ((u32)hi << 16) | (u32)lo);
      if (hs_out)
        hs_out[(size_t)((t - 1) * NB + b) * HID + colB] = hi;
    }

    grid_barrier(flags, bid, (u32)(2 * t));
  }

  // final phase C for t = TSTEPS
  if (do_c) {
    const int tp = TSTEPS;
    const int q = tid >> 6, idx = tid & 63, r2 = idx >> 5, o = idx & 31;
    const int row = bid * 2 + r2;
    const u64* hp = (const u64*)(h_ring + (size_t)(tp & 1) * NB * HID) + (size_t)row * 256 + q * 64;
    float acc = 0.f;
    #pragma unroll 8
    for (int kk = 0; kk < 64; ++kk) {
      u64 v = ld_u64_llc(&hp[kk]);
      u32 v0 = (u32)v, v1 = (u32)(v >> 32);
      float h0 = bf2f((u16)(v0 >> 16)) + bf2f((u16)(v0 & 0xFFFFu));
      float h1 = bf2f((u16)(v1 >> 16)) + bf2f((u16)(v1 & 0xFFFFu));
      int k = q * 128 + 2 * kk;
      acc += h0 * Wro[(size_t)o * HID + k] + h1 * Wro[(size_t)o * HID + k + 1];
    }
    sC[r2][o][q] = acc;
    if (idx < 2) {
      const int rowb = bid * 2 + idx;
      const u64* hp2 = (const u64*)(h_ring + (size_t)(tp & 1) * NB * HID) + (size_t)rowb * 256 + q * 64;
      float a2 = 0.f;
      #pragma unroll 8
      for (int kk = 0; kk < 64; ++kk) {
        u64 v = ld_u64_llc(&hp2[kk]);
        u32 v0 = (u32)v, v1 = (u32)(v >> 32);
        float h0 = bf2f((u16)(v0 >> 16)) + bf2f((u16)(v0 & 0xFFFFu));
        float h1 = bf2f((u16)(v1 >> 16)) + bf2f((u16)(v1 & 0xFFFFu));
        int k = q * 128 + 2 * kk;
        a2 += h0 * Wro[(size_t)32 * HID + k] + h1 * Wro[(size_t)32 * HID + k + 1];
      }
      sC[idx][32][q] = a2;
    }
    __syncthreads();
    if (tid < 66) {
      int rr = tid / 33, oo = tid % 33;
      float s = sC[rr][oo][0] + sC[rr][oo][1] + sC[rr][oo][2] + sC[rr][oo][3] + bro[oo];
      out[(size_t)((tp - 1) * NB + bid * 2 + rr) * ODIM + oo] = s;
    }
  }
}

// ---------------- output projection (big-ws path): out = hs @ W_ro^T + b_ro ----------------
__global__ void __launch_bounds__(256) out_kernel(
    const u16* __restrict__ hs_out,
    const u16* __restrict__ w_rob, const float* __restrict__ b_ro,
    float* __restrict__ out)
{
  __shared__ __attribute__((aligned(16))) u16 sOh[128][72];

  const int m0   = blockIdx.x * 128;
  const int tid  = threadIdx.x;
  const int lane = tid & 63, wave = tid >> 6;

  f32x4 acc[2][3];
  for (int a = 0; a < 2; ++a) for (int b = 0; b < 3; ++b) acc[a][b] = {0.f, 0.f, 0.f, 0.f};

  for (int kc = 0; kc < 8; ++kc) {
    __syncthreads();
    #pragma unroll
    for (int i = 0; i < 4; ++i) {
      int c = tid + 256 * i; int row = c >> 3, seg = c & 7;
      *(uint4*)&sOh[row][seg * 8] =
        *(const uint4*)&hs_out[(size_t)(m0 + row) * HID + kc * 64 + seg * 8];
    }
    __syncthreads();
    #pragma unroll
    for (int ks = 0; ks < 2; ++ks) {
      int klocal = ks * 32 + 8 * (lane >> 4);
      int kglob  = kc * 64 + klocal;
      bf16x8 ah[2];
      #pragma unroll
      for (int mf = 0; mf < 2; ++mf) {
        int rowl = wave * 32 + mf * 16 + (lane & 15);
        ah[mf] = bc8(*(const uint4*)&sOh[rowl][klocal]);
      }
      #pragma unroll
      for (int nf = 0; nf < 3; ++nf) {
        int wrow = nf * 16 + (lane & 15);
        bf16x8 bw = bc8(*(const uint4*)&w_rob[(size_t)wrow * HID + kglob]);
        #pragma unroll
        for (int mf = 0; mf < 2; ++mf)
          acc[mf][nf] = mfma_bf16(ah[mf], bw, acc[mf][nf]);
      }
    }
  }
  for (int nf = 0; nf < 3; ++nf) {
    int o = nf * 16 + (lane & 15);
    if (o < ODIM) {
      float bb = b_ro[o];
      for (int mf = 0; mf < 2; ++mf)
        for (int r = 0; r < 4; ++r) {
          int R = m0 + wave * 32 + mf * 16 + (lane >> 4) * 4 + r;
          out[(size_t)R * ODIM + o] = acc[mf][nf][r] + bb;
        }
    }
  }
}

// ---------------- launcher ----------------
extern "C" void kernel_launch(void* const* d_in, const int* in_sizes, int n_in,
                              void* d_out, int out_size, void* d_ws, size_t ws_size,
                              hipStream_t stream)
{
  const float* x   = (const float*)d_in[0];
  const float* nr  = (const float*)d_in[1];
  const float* nz  = (const float*)d_in[2];
  const float* nh  = (const float*)d_in[3];
  const float* Wxr = (const float*)d_in[4];
  const float* Wxz = (const float*)d_in[5];
  const float* Wxh = (const float*)d_in[6];
  const float* Whr = (const float*)d_in[7];
  const float* bhr = (const float*)d_in[8];
  const float* Whz = (const float*)d_in[9];
  const float* bhz = (const float*)d_in[10];
  const float* Whh = (const float*)d_in[11];
  const float* bhh = (const float*)d_in[12];
  const float* Wro = (const float*)d_in[13];
  const float* bro = (const float*)d_in[14];
  float* out = (float*)d_out;

  char* ws = (char*)d_ws;
  size_t off = 0;
  auto alloc = [&](size_t bytes) -> char* {
    char* p = ws + off;
    off += (bytes + 255) & ~(size_t)255;
    return p;
  };
  u32*  h_ring = (u32*) alloc((size_t)2 * NB * HID * 4);      // 1 MB
  u32*  g_pack = (u32*) alloc((size_t)NB * HID * 4);          // 512 KB
  float* z_buf = (float*)alloc((size_t)NB * HID * 4);         // 512 KB
  u16*  w_hb   = (u16*) alloc((size_t)3 * HID * HID * 2);     // 1.57 MB
  u16*  wx_hi  = (u16*) alloc((size_t)3 * HID * DPAD * 2);
  u16*  wx_lo  = (u16*) alloc((size_t)3 * HID * DPAD * 2);
  u16*  w_rob  = (u16*) alloc((size_t)OPAD * HID * 2);
  u32*  flags  = (u32*) alloc((size_t)NBLK * 32 * 4);
  size_t small_need = off;
  if (ws_size < small_need) return;   // clean numeric failure, not a crash

  u16* hs_out = (u16*)(ws + off);
  size_t big_need = off + (size_t)TBROWS * HID * 2 + 256;     // +134.2 MB
  bool big = (ws_size >= big_need);
  if (!big) hs_out = nullptr;

  hipMemsetAsync(flags, 0, (size_t)NBLK * 32 * 4, stream);
  hipMemsetAsync(h_ring, 0, (size_t)2 * NB * HID * 4, stream);   // h0 = 0

  prep_kernel<<<512, 256, 0, stream>>>(Whr, Whz, Whh, Wxr, Wxz, Wxh, Wro,
                                       w_hb, wx_hi, wx_lo, w_rob);

  recur_kernel<<<NBLK, 256, 0, stream>>>(
      x, nr, nz, nh, bhr, bhz, bhh, wx_hi, wx_lo, w_hb,
      h_ring, g_pack, z_buf, flags, hs_out, Wro, bro, out, big ? 0 : 1);

  if (big)
    out_kernel<<<TBROWS / 128, 256, 0, stream>>>(hs_out, w_rob, bro, out);
}

// Round 4
// 9244.232 us; speedup vs baseline: 2.0711x; 2.0711x over previous
//
#include <hip/hip_runtime.h>
#include <stdint.h>

// ---------------- problem constants ----------------
#define TSTEPS 512
#define NB     256
#define DIN    85
#define DPAD   96
#define HID    512
#define ODIM   33
#define OPAD   48
#define TBROWS (TSTEPS*NB)
#define NBLK   256          // 16 strips x 16 parts; 42KB LDS -> >=3 blocks/CU fit, deadlock-proof
#define SROWS  16           // batch rows per strip

typedef unsigned int u32;
typedef unsigned short u16;
typedef unsigned long long u64;
typedef __bf16 bf16x8 __attribute__((ext_vector_type(8)));
typedef float  f32x4  __attribute__((ext_vector_type(4)));

__device__ __forceinline__ u16 f2bf(float f) {
  u32 u = __float_as_uint(f);
  return (u16)((u + 0x7FFFu + ((u >> 16) & 1u)) >> 16);   // RNE
}
__device__ __forceinline__ float bf2f(u16 h) {
  return __uint_as_float(((u32)h) << 16);
}
__device__ __forceinline__ bf16x8 bc8(uint4 v) { return __builtin_bit_cast(bf16x8, v); }
__device__ __forceinline__ f32x4 mfma_bf16(bf16x8 a, bf16x8 b, f32x4 c) {
  return __builtin_amdgcn_mfma_f32_16x16x32_bf16(a, b, c, 0, 0, 0);
}
__device__ __forceinline__ float fsigmoid(float x) { return 1.0f / (1.0f + __expf(-x)); }
__device__ __forceinline__ float ftanh(float x)    { return 2.0f / (1.0f + __expf(-2.0f*x)) - 1.0f; }

// agent-scope (LLC-coherent) ops for cross-block mutable data
__device__ __forceinline__ void st_u32_llc(u32* p, u32 v) {
  __hip_atomic_store(p, v, __ATOMIC_RELAXED, __HIP_MEMORY_SCOPE_AGENT);
}
__device__ __forceinline__ u32 ld_u32_llc(const u32* p) {
  return __hip_atomic_load(p, __ATOMIC_RELAXED, __HIP_MEMORY_SCOPE_AGENT);
}
__device__ __forceinline__ u64 ld_u64_llc(const u64* p) {
  return __hip_atomic_load(p, __ATOMIC_RELAXED, __HIP_MEMORY_SCOPE_AGENT);
}
__device__ __forceinline__ void st_f32_llc(float* p, float v) {
  __hip_atomic_store(p, v, __ATOMIC_RELAXED, __HIP_MEMORY_SCOPE_AGENT);
}
__device__ __forceinline__ float ld_f32_llc(const float* p) {
  return __hip_atomic_load(p, __ATOMIC_RELAXED, __HIP_MEMORY_SCOPE_AGENT);
}

// ---------------- prep: bf16 weight conversions ----------------
__global__ void __launch_bounds__(256) prep_kernel(
    const float* __restrict__ Whr, const float* __restrict__ Whz, const float* __restrict__ Whh,
    const float* __restrict__ Wxr, const float* __restrict__ Wxz, const float* __restrict__ Wxh,
    const float* __restrict__ Wro,
    u16* __restrict__ w_hb, u16* __restrict__ wx_hi, u16* __restrict__ wx_lo,
    u16* __restrict__ w_rob)
{
  int tid = blockIdx.x * blockDim.x + threadIdx.x;
  int np  = gridDim.x * blockDim.x;
  for (int i = tid; i < 3 * HID * HID; i += np) {
    int m = i / (HID * HID), r = i % (HID * HID);
    const float* src = (m == 0) ? Whr : ((m == 1) ? Whz : Whh);
    w_hb[i] = f2bf(src[r]);
  }
  for (int i = tid; i < 3 * HID * DPAD; i += np) {
    int m = i / (HID * DPAD), r = i % (HID * DPAD);
    int row = r / DPAD, k = r % DPAD;
    const float* src = (m == 0) ? Wxr : ((m == 1) ? Wxz : Wxh);
    u16 hi = 0, lo = 0;
    if (k < DIN) {
      float v = src[row * DIN + k];
      hi = f2bf(v);
      lo = f2bf(v - bf2f(hi));
    }
    wx_hi[i] = hi; wx_lo[i] = lo;
  }
  for (int i = tid; i < OPAD * HID; i += np) {
    int row = i / HID, k = i % HID;
    w_rob[i] = (row < ODIM) ? f2bf(Wro[row * HID + k]) : (u16)0;
  }
}

// ---------------- persistent recurrence kernel ----------------
#define LROW 520   // padded LDS row stride (u16): 1040B = 65*16B -> b128 reads ~conflict-free

__global__ void __launch_bounds__(256, 1) recur_kernel(
    const float* __restrict__ x,  const float* __restrict__ nr,
    const float* __restrict__ nz, const float* __restrict__ nh,
    const float* __restrict__ bhr, const float* __restrict__ bhz, const float* __restrict__ bhh,
    const u16* __restrict__ wx_hi, const u16* __restrict__ wx_lo, const u16* __restrict__ w_hb,
    u32* __restrict__ h_pk, u32* __restrict__ g_pk,
    float* __restrict__ z_buf, u32* __restrict__ flags,
    u16* __restrict__ hs_out,
    const float* __restrict__ Wro, const float* __restrict__ bro, float* __restrict__ out,
    int do_c)
{
  // union strip buffer: A phase = split h (hi,lo); B phase = split g (hi,lo); C = f32 scratch
  __shared__ __attribute__((aligned(16))) u16 sBig[2 * SROWS * LROW];   // 33280 B
  __shared__ __attribute__((aligned(16))) u16 sXh[SROWS][104];          // 3328 B
  __shared__ __attribute__((aligned(16))) u16 sXl[SROWS][104];          // 3328 B
  __shared__ __attribute__((aligned(16))) float sC[2][64][4];           // 2048 B

  u16 (*sHh)[LROW] = (u16(*)[LROW])sBig;
  u16 (*sHl)[LROW] = (u16(*)[LROW])(sBig + SROWS * LROW);
  u16 (*sGh)[LROW] = sHh;
  u16 (*sGl)[LROW] = sHl;
  float* sC2 = (float*)sBig;

  const int bid  = blockIdx.x;
  const int tid  = threadIdx.x;
  const int lane = tid & 63;
  const int wave = tid >> 6;
  const int strip = bid >> 4;     // 0..15 (16 batch rows each)
  const int part  = bid & 15;

  // ---- phase A geometry: [16 rows x 64 cols] over [256 x 1024] (R cols | Z cols) ----
  const int isZ = part >= 8;
  const int ncA = (part & 7) * 64;
  const u16*  WA   = w_hb  + (size_t)(isZ ? 1 : 0) * HID * HID;
  const u16*  WXAh = wx_hi + (size_t)(isZ ? 1 : 0) * HID * DPAD;
  const u16*  WXAl = wx_lo + (size_t)(isZ ? 1 : 0) * HID * DPAD;
  const float* nA  = isZ ? nz : nr;
  const int rowl  = lane & 15;                    // fragment row (batch within strip)
  const int colA  = ncA + wave * 16 + rowl;       // wave = n-tile
  const float biasA = (isZ ? bhz : bhr)[colA];

  // ---- phase B geometry: [16 rows x 32 cols]; waves: n-tile x k-half ----
  const int ncB  = part * 32;
  const u16*  WH   = w_hb  + (size_t)2 * HID * HID;
  const u16*  WXBh = wx_hi + (size_t)2 * HID * DPAD;
  const u16*  WXBl = wx_lo + (size_t)2 * HID * DPAD;
  const int ntB = wave & 1;
  const int khB = wave >> 1;
  const int colB = ncB + ntB * 16 + rowl;
  const float biasB = bhh[colB];

  float h_old[4] = {0.f, 0.f, 0.f, 0.f};   // fp32 state (khB==0 waves own update)

  // zero x-buffer k-pads once (cols 85..103)
  for (int c = tid; c < SROWS * (104 - DIN); c += 256) {
    int row = c / (104 - DIN), k = DIN + c % (104 - DIN);
    sXh[row][k] = 0; sXl[row][k] = 0;
  }
  // stage xA for t=1
  {
    const size_t xoff = (size_t)(strip * SROWS) * DIN;
    for (int c = tid; c < SROWS * DIN; c += 256) {
      int row = c / DIN, k = c - row * DIN;
      float v = x[xoff + c] + nA[xoff + c];
      u16 hi = f2bf(v);
      sXh[row][k] = hi;
      sXl[row][k] = f2bf(v - bf2f(hi));
    }
  }

  for (int t = 1; t <= TSTEPS; ++t) {
    // ---------- phase C (small-ws inline out-projection) for step t-1 ----------
    if (do_c && t >= 2) {
      const int row = bid;                   // one batch row per block
      const int o = tid >> 3, q = tid & 7;
      const int base = row * HID + q * 64;
      float a = 0.f;
      #pragma unroll 8
      for (int k2 = 0; k2 < 64; ++k2) {
        u32 v = ld_u32_llc(&h_pk[base + k2]);
        a += (bf2f((u16)(v >> 16)) + bf2f((u16)(v & 0xFFFFu))) * Wro[(size_t)o * HID + q * 64 + k2];
      }
      __syncthreads();            // sBig (sC2) free of phase-B data hazards
      sC2[o * 8 + q] = a;
      if (tid < 8) {
        float a2 = 0.f;
        const int base2 = row * HID + tid * 64;
        #pragma unroll 8
        for (int k2 = 0; k2 < 64; ++k2) {
          u32 v = ld_u32_llc(&h_pk[base2 + k2]);
          a2 += (bf2f((u16)(v >> 16)) + bf2f((u16)(v & 0xFFFFu))) * Wro[(size_t)32 * HID + tid * 64 + k2];
        }
        sC2[32 * 8 + tid] = a2;
      }
      __syncthreads();
      if (tid < ODIM) {
        float s = bro[tid];
        #pragma unroll
        for (int q2 = 0; q2 < 8; ++q2) s += sC2[tid * 8 + q2];
        out[(size_t)((t - 2) * NB + row) * ODIM + tid] = s;
      }
      __syncthreads();
    }

    // ================= PHASE A: R and Z =================
    // one-shot split-h strip staging: 16 rows x 512 cols packed u32 = 32KB
    {
      const u64* hsrc = (const u64*)h_pk;       // u64 = 2 packed cols
      u64 hreg[SROWS];
      #pragma unroll
      for (int i = 0; i < SROWS; ++i)
        hreg[i] = ld_u64_llc(&hsrc[(size_t)(strip * SROWS + i) * 256 + tid]);
      #pragma unroll
      for (int i = 0; i < SROWS; ++i) {
        u32 v0 = (u32)hreg[i], v1 = (u32)(hreg[i] >> 32);
        *(u32*)&sHh[i][tid * 2] = (v0 >> 16) | (v1 & 0xFFFF0000u);
        *(u32*)&sHl[i][tid * 2] = (v0 & 0xFFFFu) | (v1 << 16);
      }
    }
    __syncthreads();

    f32x4 accA = {0.f, 0.f, 0.f, 0.f};
    // x-projection (K=96; split x, split Wx: 3 MFMAs per 32-k)
    #pragma unroll
    for (int ks = 0; ks < 3; ++ks) {
      int kk = ks * 32 + 8 * (lane >> 4);
      bf16x8 wh = bc8(*(const uint4*)&WXAh[(size_t)colA * DPAD + kk]);
      bf16x8 wl = bc8(*(const uint4*)&WXAl[(size_t)colA * DPAD + kk]);
      bf16x8 xh = bc8(*(const uint4*)&sXh[rowl][kk]);
      bf16x8 xl = bc8(*(const uint4*)&sXl[rowl][kk]);
      accA = mfma_bf16(xh, wh, accA);
      accA = mfma_bf16(xl, wh, accA);
      accA = mfma_bf16(xh, wl, accA);
    }
    // h GEMM (K=512, split h)
    #pragma unroll
    for (int kk16 = 0; kk16 < 16; ++kk16) {
      int k = kk16 * 32 + 8 * (lane >> 4);
      bf16x8 bw = bc8(*(const uint4*)&WA[(size_t)colA * HID + k]);
      bf16x8 ah = bc8(*(const uint4*)&sHh[rowl][k]);
      bf16x8 al = bc8(*(const uint4*)&sHl[rowl][k]);
      accA = mfma_bf16(ah, bw, accA);
      accA = mfma_bf16(al, bw, accA);
    }

    // epilogue A (precise h for R*h comes straight from the staged LDS strip)
    #pragma unroll
    for (int r = 0; r < 4; ++r) {
      int rowm = (lane >> 4) * 4 + r;
      int grow = strip * SROWS + rowm;
      float val = fsigmoid(accA[r] + biasA);
      size_t idx = (size_t)grow * HID + colA;
      if (!isZ) {
        float hcur = bf2f(sHh[rowm][colA]) + bf2f(sHl[rowm][colA]);
        float g = val * hcur;
        u16 gh = f2bf(g);
        u16 gl = f2bf(g - bf2f(gh));
        st_u32_llc(&g_pk[idx], ((u32)gh << 16) | (u32)gl);
      } else {
        st_f32_llc(&z_buf[idx], val);
      }
    }

    // arrive(2t-1)
    __syncthreads();
    if (tid == 0)
      __hip_atomic_store(&flags[bid * 16], (u32)(2 * t - 1), __ATOMIC_RELEASE, __HIP_MEMORY_SCOPE_AGENT);

    // overlap: stage xB(t) during barrier wait
    {
      const size_t xoff = (size_t)((t - 1) * NB + strip * SROWS) * DIN;
      for (int c = tid; c < SROWS * DIN; c += 256) {
        int row = c / DIN, k = c - row * DIN;
        float v = x[xoff + c] + nh[xoff + c];
        u16 hi = f2bf(v);
        sXh[row][k] = hi;
        sXl[row][k] = f2bf(v - bf2f(hi));
      }
    }
    // wait(2t-1)
    if (wave == 0) {
      u32 target = (u32)(2 * t - 1);
      for (;;) {
        u32 a0 = ld_u32_llc(&flags[lane * 16]);
        u32 a1 = ld_u32_llc(&flags[(lane + 64) * 16]);
        u32 a2 = ld_u32_llc(&flags[(lane + 128) * 16]);
        u32 a3 = ld_u32_llc(&flags[(lane + 192) * 16]);
        if (__all(a0 >= target && a1 >= target && a2 >= target && a3 >= target)) break;
        __builtin_amdgcn_s_sleep(1);
      }
    }
    __syncthreads();

    // ================= PHASE B: Hh + state update =================
    // early: Z for the update (khB==0 waves)
    float zv[4];
    if (khB == 0) {
      #pragma unroll
      for (int r = 0; r < 4; ++r) {
        int brow = strip * SROWS + (lane >> 4) * 4 + r;
        zv[r] = ld_f32_llc(&z_buf[(size_t)brow * HID + colB]);
      }
    }
    // one-shot split-g strip staging: 16 rows x 512 packed u32 = 32KB
    {
      const u64* gsrc = (const u64*)g_pk;
      u64 greg[SROWS];
      #pragma unroll
      for (int i = 0; i < SROWS; ++i)
        greg[i] = ld_u64_llc(&gsrc[(size_t)(strip * SROWS + i) * 256 + tid]);
      #pragma unroll
      for (int i = 0; i < SROWS; ++i) {
        u32 v0 = (u32)greg[i], v1 = (u32)(greg[i] >> 32);
        *(u32*)&sGh[i][tid * 2] = (v0 >> 16) | (v1 & 0xFFFF0000u);
        *(u32*)&sGl[i][tid * 2] = (v0 & 0xFFFFu) | (v1 << 16);
      }
    }
    __syncthreads();

    f32x4 accB = {0.f, 0.f, 0.f, 0.f};
    if (khB == 0) {   // x-projection on k-lower waves
      #pragma unroll
      for (int ks = 0; ks < 3; ++ks) {
        int kk = ks * 32 + 8 * (lane >> 4);
        bf16x8 wh = bc8(*(const uint4*)&WXBh[(size_t)colB * DPAD + kk]);
        bf16x8 wl = bc8(*(const uint4*)&WXBl[(size_t)colB * DPAD + kk]);
        bf16x8 xh = bc8(*(const uint4*)&sXh[rowl][kk]);
        bf16x8 xl = bc8(*(const uint4*)&sXl[rowl][kk]);
        accB = mfma_bf16(xh, wh, accB);
        accB = mfma_bf16(xl, wh, accB);
        accB = mfma_bf16(xh, wl, accB);
      }
    }
    #pragma unroll
    for (int f = 0; f < 8; ++f) {
      int k = khB * 256 + f * 32 + 8 * (lane >> 4);
      bf16x8 bw = bc8(*(const uint4*)&WH[(size_t)colB * HID + k]);
      bf16x8 gh = bc8(*(const uint4*)&sGh[rowl][k]);
      bf16x8 gl = bc8(*(const uint4*)&sGl[rowl][k]);
      accB = mfma_bf16(gh, bw, accB);
      accB = mfma_bf16(gl, bw, accB);
    }
    if (khB == 1) *(f32x4*)&sC[ntB][lane][0] = accB;
    __syncthreads();

    if (khB == 0) {
      f32x4 oth = *(const f32x4*)&sC[ntB][lane][0];
      accB[0] += oth[0]; accB[1] += oth[1]; accB[2] += oth[2]; accB[3] += oth[3];
      #pragma unroll
      for (int r = 0; r < 4; ++r) {
        int brow = strip * SROWS + (lane >> 4) * 4 + r;
        float hh = ftanh(accB[r] + biasB);
        float hn = zv[r] * h_old[r] + (1.0f - zv[r]) * hh;
        h_old[r] = hn;
        u16 hi = f2bf(hn);
        u16 lo = f2bf(hn - bf2f(hi));
        st_u32_llc(&h_pk[(size_t)brow * HID + colB], ((u32)hi << 16) | (u32)lo);
        if (hs_out)
          hs_out[(size_t)((t - 1) * NB + brow) * HID + colB] = hi;
      }
    }

    // arrive(2t)
    __syncthreads();
    if (tid == 0)
      __hip_atomic_store(&flags[bid * 16], (u32)(2 * t), __ATOMIC_RELEASE, __HIP_MEMORY_SCOPE_AGENT);

    // overlap: stage xA(t+1) during barrier wait
    if (t < TSTEPS) {
      const size_t xoff = (size_t)(t * NB + strip * SROWS) * DIN;
      for (int c = tid; c < SROWS * DIN; c += 256) {
        int row = c / DIN, k = c - row * DIN;
        float v = x[xoff + c] + nA[xoff + c];
        u16 hi = f2bf(v);
        sXh[row][k] = hi;
        sXl[row][k] = f2bf(v - bf2f(hi));
      }
    }
    // wait(2t)
    if (wave == 0) {
      u32 target = (u32)(2 * t);
      for (;;) {
        u32 a0 = ld_u32_llc(&flags[lane * 16]);
        u32 a1 = ld_u32_llc(&flags[(lane + 64) * 16]);
        u32 a2 = ld_u32_llc(&flags[(lane + 128) * 16]);
        u32 a3 = ld_u32_llc(&flags[(lane + 192) * 16]);
        if (__all(a0 >= target && a1 >= target && a2 >= target && a3 >= target)) break;
        __builtin_amdgcn_s_sleep(1);
      }
    }
    __syncthreads();
  }

  // final phase C (small-ws) for t = TSTEPS
  if (do_c) {
    const int row = bid;
    const int o = tid >> 3, q = tid & 7;
    const int base = row * HID + q * 64;
    float a = 0.f;
    #pragma unroll 8
    for (int k2 = 0; k2 < 64; ++k2) {
      u32 v = ld_u32_llc(&h_pk[base + k2]);
      a += (bf2f((u16)(v >> 16)) + bf2f((u16)(v & 0xFFFFu))) * Wro[(size_t)o * HID + q * 64 + k2];
    }
    __syncthreads();
    sC2[o * 8 + q] = a;
    if (tid < 8) {
      float a2 = 0.f;
      const int base2 = row * HID + tid * 64;
      #pragma unroll 8
      for (int k2 = 0; k2 < 64; ++k2) {
        u32 v = ld_u32_llc(&h_pk[base2 + k2]);
        a2 += (bf2f((u16)(v >> 16)) + bf2f((u16)(v & 0xFFFFu))) * Wro[(size_t)32 * HID + tid * 64 + k2];
      }
      sC2[32 * 8 + tid] = a2;
    }
    __syncthreads();
    if (tid < ODIM) {
      float s = bro[tid];
      #pragma unroll
      for (int q2 = 0; q2 < 8; ++q2) s += sC2[tid * 8 + q2];
      out[(size_t)((TSTEPS - 1) * NB + row) * ODIM + tid] = s;
    }
  }
}

// ---------------- output projection (big-ws path) ----------------
__global__ void __launch_bounds__(256) out_kernel(
    const u16* __restrict__ hs_out,
    const u16* __restrict__ w_rob, const float* __restrict__ b_ro,
    float* __restrict__ out)
{
  __shared__ __attribute__((aligned(16))) u16 sOh[128][72];

  const int m0   = blockIdx.x * 128;
  const int tid  = threadIdx.x;
  const int lane = tid & 63, wave = tid >> 6;

  f32x4 acc[2][3];
  for (int a = 0; a < 2; ++a) for (int b = 0; b < 3; ++b) acc[a][b] = {0.f, 0.f, 0.f, 0.f};

  for (int kc = 0; kc < 8; ++kc) {
    __syncthreads();
    #pragma unroll
    for (int i = 0; i < 4; ++i) {
      int c = tid + 256 * i; int row = c >> 3, seg = c & 7;
      *(uint4*)&sOh[row][seg * 8] =
        *(const uint4*)&hs_out[(size_t)(m0 + row) * HID + kc * 64 + seg * 8];
    }
    __syncthreads();
    #pragma unroll
    for (int ks = 0; ks < 2; ++ks) {
      int klocal = ks * 32 + 8 * (lane >> 4);
      int kglob  = kc * 64 + klocal;
      bf16x8 ah[2];
      #pragma unroll
      for (int mf = 0; mf < 2; ++mf) {
        int rowl = wave * 32 + mf * 16 + (lane & 15);
        ah[mf] = bc8(*(const uint4*)&sOh[rowl][klocal]);
      }
      #pragma unroll
      for (int nf = 0; nf < 3; ++nf) {
        int wrow = nf * 16 + (lane & 15);
        bf16x8 bw = bc8(*(const uint4*)&w_rob[(size_t)wrow * HID + kglob]);
        #pragma unroll
        for (int mf = 0; mf < 2; ++mf)
          acc[mf][nf] = mfma_bf16(ah[mf], bw, acc[mf][nf]);
      }
    }
  }
  for (int nf = 0; nf < 3; ++nf) {
    int o = nf * 16 + (lane & 15);
    if (o < ODIM) {
      float bb = b_ro[o];
      for (int mf = 0; mf < 2; ++mf)
        for (int r = 0; r < 4; ++r) {
          int R = m0 + wave * 32 + mf * 16 + (lane >> 4) * 4 + r;
          out[(size_t)R * ODIM + o] = acc[mf][nf][r] + bb;
        }
    }
  }
}

// ---------------- launcher ----------------
extern "C" void kernel_launch(void* const* d_in, const int* in_sizes, int n_in,
                              void* d_out, int out_size, void* d_ws, size_t ws_size,
                              hipStream_t stream)
{
  const float* x   = (const float*)d_in[0];
  const float* nr  = (const float*)d_in[1];
  const float* nz  = (const float*)d_in[2];
  const float* nh  = (const float*)d_in[3];
  const float* Wxr = (const float*)d_in[4];
  const float* Wxz = (const float*)d_in[5];
  const float* Wxh = (const float*)d_in[6];
  const float* Whr = (const float*)d_in[7];
  const float* bhr = (const float*)d_in[8];
  const float* Whz = (const float*)d_in[9];
  const float* bhz = (const float*)d_in[10];
  const float* Whh = (const float*)d_in[11];
  const float* bhh = (const float*)d_in[12];
  const float* Wro = (const float*)d_in[13];
  const float* bro = (const float*)d_in[14];
  float* out = (float*)d_out;

  char* ws = (char*)d_ws;
  size_t off = 0;
  auto alloc = [&](size_t bytes) -> char* {
    char* p = ws + off;
    off += (bytes + 255) & ~(size_t)255;
    return p;
  };
  u32*  h_pk  = (u32*) alloc((size_t)NB * HID * 4);       // packed hi|lo h state
  u32*  g_pk  = (u32*) alloc((size_t)NB * HID * 4);       // packed hi|lo R*h
  float* z_buf= (float*)alloc((size_t)NB * HID * 4);
  u16*  w_hb  = (u16*) alloc((size_t)3 * HID * HID * 2);
  u16*  wx_hi = (u16*) alloc((size_t)3 * HID * DPAD * 2);
  u16*  wx_lo = (u16*) alloc((size_t)3 * HID * DPAD * 2);
  u16*  w_rob = (u16*) alloc((size_t)OPAD * HID * 2);
  u32*  flags = (u32*) alloc((size_t)NBLK * 16 * 4);
  size_t small_need = off;
  if (ws_size < small_need) return;   // fail numerically, never scribble

  u16* hs_out = (u16*)(ws + off);
  size_t big_need = off + (size_t)TBROWS * HID * 2 + 256;
  bool big = (ws_size >= big_need);
  if (!big) hs_out = nullptr;

  hipMemsetAsync(flags, 0, (size_t)NBLK * 16 * 4, stream);
  hipMemsetAsync(h_pk,  0, (size_t)NB * HID * 4, stream);   // h0 = 0

  prep_kernel<<<512, 256, 0, stream>>>(Whr, Whz, Whh, Wxr, Wxz, Wxh, Wro,
                                       w_hb, wx_hi, wx_lo, w_rob);

  recur_kernel<<<NBLK, 256, 0, stream>>>(
      x, nr, nz, nh, bhr, bhz, bhh, wx_hi, wx_lo, w_hb,
      h_pk, g_pk, z_buf, flags, hs_out, Wro, bro, out, big ? 0 : 1);

  if (big)
    out_kernel<<<TBROWS / 128, 256, 0, stream>>>(hs_out, w_rob, bro, out);
}

// Round 5
// 5271.474 us; speedup vs baseline: 3.6319x; 1.7536x over previous
//
#include <hip/hip_runtime.h>
#include <stdint.h>

// ---------------- problem constants ----------------
#define TSTEPS 512
#define NB     256
#define DIN    85
#define DPAD   96
#define HID    512
#define ODIM   33
#define OPAD   48
#define TBROWS (TSTEPS*NB)
#define NBLK   256          // 16 strip-groups x 16 parts; 42KB LDS, deadlock-proof residency
#define SROWS  16           // batch rows per strip-group

typedef unsigned int u32;
typedef unsigned short u16;
typedef unsigned long long u64;
typedef __bf16 bf16x8 __attribute__((ext_vector_type(8)));
typedef float  f32x4  __attribute__((ext_vector_type(4)));

__device__ __forceinline__ u16 f2bf(float f) {
  u32 u = __float_as_uint(f);
  return (u16)((u + 0x7FFFu + ((u >> 16) & 1u)) >> 16);   // RNE
}
__device__ __forceinline__ float bf2f(u16 h) {
  return __uint_as_float(((u32)h) << 16);
}
__device__ __forceinline__ bf16x8 bc8(uint4 v) { return __builtin_bit_cast(bf16x8, v); }
__device__ __forceinline__ f32x4 mfma_bf16(bf16x8 a, bf16x8 b, f32x4 c) {
  return __builtin_amdgcn_mfma_f32_16x16x32_bf16(a, b, c, 0, 0, 0);
}
__device__ __forceinline__ float fsigmoid(float x) { return 1.0f / (1.0f + __expf(-x)); }
__device__ __forceinline__ float ftanh(float x)    { return 2.0f / (1.0f + __expf(-2.0f*x)) - 1.0f; }

// agent-scope (LLC-coherent) ops for cross-block mutable data (all RELAXED —
// ordering comes from __syncthreads()'s vmcnt(0) drain before the flag store)
__device__ __forceinline__ void st_u32_llc(u32* p, u32 v) {
  __hip_atomic_store(p, v, __ATOMIC_RELAXED, __HIP_MEMORY_SCOPE_AGENT);
}
__device__ __forceinline__ u32 ld_u32_llc(const u32* p) {
  return __hip_atomic_load(p, __ATOMIC_RELAXED, __HIP_MEMORY_SCOPE_AGENT);
}
__device__ __forceinline__ u64 ld_u64_llc(const u64* p) {
  return __hip_atomic_load(p, __ATOMIC_RELAXED, __HIP_MEMORY_SCOPE_AGENT);
}
__device__ __forceinline__ void st_f32_llc(float* p, float v) {
  __hip_atomic_store(p, v, __ATOMIC_RELAXED, __HIP_MEMORY_SCOPE_AGENT);
}
__device__ __forceinline__ float ld_f32_llc(const float* p) {
  return __hip_atomic_load(p, __ATOMIC_RELAXED, __HIP_MEMORY_SCOPE_AGENT);
}

// ---------------- prep: bf16 weight conversions ----------------
__global__ void __launch_bounds__(256) prep_kernel(
    const float* __restrict__ Whr, const float* __restrict__ Whz, const float* __restrict__ Whh,
    const float* __restrict__ Wxr, const float* __restrict__ Wxz, const float* __restrict__ Wxh,
    const float* __restrict__ Wro,
    u16* __restrict__ w_hb, u16* __restrict__ wx_hi, u16* __restrict__ wx_lo,
    u16* __restrict__ w_rob)
{
  int tid = blockIdx.x * blockDim.x + threadIdx.x;
  int np  = gridDim.x * blockDim.x;
  for (int i = tid; i < 3 * HID * HID; i += np) {
    int m = i / (HID * HID), r = i % (HID * HID);
    const float* src = (m == 0) ? Whr : ((m == 1) ? Whz : Whh);
    w_hb[i] = f2bf(src[r]);
  }
  for (int i = tid; i < 3 * HID * DPAD; i += np) {
    int m = i / (HID * DPAD), r = i % (HID * DPAD);
    int row = r / DPAD, k = r % DPAD;
    const float* src = (m == 0) ? Wxr : ((m == 1) ? Wxz : Wxh);
    u16 hi = 0, lo = 0;
    if (k < DIN) {
      float v = src[row * DIN + k];
      hi = f2bf(v);
      lo = f2bf(v - bf2f(hi));
    }
    wx_hi[i] = hi; wx_lo[i] = lo;
  }
  for (int i = tid; i < OPAD * HID; i += np) {
    int row = i / HID, k = i % HID;
    w_rob[i] = (row < ODIM) ? f2bf(Wro[row * HID + k]) : (u16)0;
  }
}

// ---------------- persistent recurrence kernel ----------------
#define LROW 520   // padded LDS row stride (u16)

__global__ void __launch_bounds__(256, 1) recur_kernel(
    const float* __restrict__ x,  const float* __restrict__ nr,
    const float* __restrict__ nz, const float* __restrict__ nh,
    const float* __restrict__ bhr, const float* __restrict__ bhz, const float* __restrict__ bhh,
    const u16* __restrict__ wx_hi, const u16* __restrict__ wx_lo, const u16* __restrict__ w_hb,
    u32* __restrict__ h_pk, u32* __restrict__ g_pk,
    float* __restrict__ z_buf, u32* __restrict__ flags,
    u16* __restrict__ hs_out,
    const float* __restrict__ Wro, const float* __restrict__ bro, float* __restrict__ out,
    int do_c)
{
  // union strip buffer: A = split h (hi,lo); B = split g (hi,lo); C = f32 scratch
  __shared__ __attribute__((aligned(16))) u16 sBig[2 * SROWS * LROW];   // 33280 B
  __shared__ __attribute__((aligned(16))) u16 sXh[SROWS][104];          // 3328 B
  __shared__ __attribute__((aligned(16))) u16 sXl[SROWS][104];          // 3328 B
  __shared__ __attribute__((aligned(16))) float sC[2][64][4];           // 2048 B

  u16 (*sHh)[LROW] = (u16(*)[LROW])sBig;
  u16 (*sHl)[LROW] = (u16(*)[LROW])(sBig + SROWS * LROW);
  u16 (*sGh)[LROW] = sHh;
  u16 (*sGl)[LROW] = sHl;
  float* sC2 = (float*)sBig;

  const int bid  = blockIdx.x;
  const int tid  = threadIdx.x;
  const int lane = tid & 63;
  const int wave = tid >> 6;
  // group members share bid%8 -> same-XCD heuristic for flag/data locality
  const int strip = bid & 15;     // group id (16 batch rows)
  const int part  = bid >> 4;     // member 0..15

  u32* gflag = flags + strip * 16;   // one 64B line per group

  // ---- phase A geometry: [16 rows x 64 cols] over [256 x 1024] (R cols | Z cols) ----
  const int isZ = part >= 8;
  const int ncA = (part & 7) * 64;
  const u16*  WA   = w_hb  + (size_t)(isZ ? 1 : 0) * HID * HID;
  const u16*  WXAh = wx_hi + (size_t)(isZ ? 1 : 0) * HID * DPAD;
  const u16*  WXAl = wx_lo + (size_t)(isZ ? 1 : 0) * HID * DPAD;
  const float* nA  = isZ ? nz : nr;
  const int rowl  = lane & 15;                    // fragment row (batch within strip)
  const int colA  = ncA + wave * 16 + rowl;       // wave = n-tile
  const float biasA = (isZ ? bhz : bhr)[colA];

  // ---- phase B geometry: [16 rows x 32 cols]; waves: n-tile x k-half ----
  const int ncB  = part * 32;
  const u16*  WH   = w_hb  + (size_t)2 * HID * HID;
  const u16*  WXBh = wx_hi + (size_t)2 * HID * DPAD;
  const u16*  WXBl = wx_lo + (size_t)2 * HID * DPAD;
  const int ntB = wave & 1;
  const int khB = wave >> 1;
  const int colB = ncB + ntB * 16 + rowl;
  const float biasB = bhh[colB];

  float h_old[4] = {0.f, 0.f, 0.f, 0.f};   // fp32 state (khB==0 waves own update)

  // zero x-buffer k-pads once (cols 85..103)
  for (int c = tid; c < SROWS * (104 - DIN); c += 256) {
    int row = c / (104 - DIN), k = DIN + c % (104 - DIN);
    sXh[row][k] = 0; sXl[row][k] = 0;
  }
  // stage xA for t=1
  {
    const size_t xoff = (size_t)(strip * SROWS) * DIN;
    for (int c = tid; c < SROWS * DIN; c += 256) {
      int row = c / DIN, k = c - row * DIN;
      float v = x[xoff + c] + nA[xoff + c];
      u16 hi = f2bf(v);
      sXh[row][k] = hi;
      sXl[row][k] = f2bf(v - bf2f(hi));
    }
  }

  for (int t = 1; t <= TSTEPS; ++t) {
    // ---------- phase C (small-ws inline out-projection) for step t-2 ----------
    if (do_c && t >= 2) {
      const int row = strip * SROWS + (part);    // 16 rows x 16 parts = all 256 rows
      const int o = tid >> 3, q = tid & 7;
      const int base = row * HID + q * 64;
      float a = 0.f;
      #pragma unroll 8
      for (int k2 = 0; k2 < 64; ++k2) {
        u32 v = ld_u32_llc(&h_pk[base + k2]);
        a += (bf2f((u16)(v >> 16)) + bf2f((u16)(v & 0xFFFFu))) * Wro[(size_t)o * HID + q * 64 + k2];
      }
      __syncthreads();            // sBig (sC2) free of phase-B LDS hazards
      sC2[o * 8 + q] = a;
      if (tid < 8) {
        float a2 = 0.f;
        const int base2 = row * HID + tid * 64;
        #pragma unroll 8
        for (int k2 = 0; k2 < 64; ++k2) {
          u32 v = ld_u32_llc(&h_pk[base2 + k2]);
          a2 += (bf2f((u16)(v >> 16)) + bf2f((u16)(v & 0xFFFFu))) * Wro[(size_t)32 * HID + tid * 64 + k2];
        }
        sC2[32 * 8 + tid] = a2;
      }
      __syncthreads();
      if (tid < ODIM) {
        float s = bro[tid];
        #pragma unroll
        for (int q2 = 0; q2 < 8; ++q2) s += sC2[tid * 8 + q2];
        out[(size_t)((t - 2) * NB + row) * ODIM + tid] = s;
      }
      __syncthreads();
    }

    // ================= PHASE A: R and Z =================
    // one-shot split-h strip staging: 16 rows x 512 cols packed u32 = 32KB
    {
      const u64* hsrc = (const u64*)h_pk;       // u64 = 2 packed cols
      u64 hreg[SROWS];
      #pragma unroll
      for (int i = 0; i < SROWS; ++i)
        hreg[i] = ld_u64_llc(&hsrc[(size_t)(strip * SROWS + i) * 256 + tid]);
      #pragma unroll
      for (int i = 0; i < SROWS; ++i) {
        u32 v0 = (u32)hreg[i], v1 = (u32)(hreg[i] >> 32);
        *(u32*)&sHh[i][tid * 2] = (v0 >> 16) | (v1 & 0xFFFF0000u);
        *(u32*)&sHl[i][tid * 2] = (v0 & 0xFFFFu) | (v1 << 16);
      }
    }
    __syncthreads();

    f32x4 accA = {0.f, 0.f, 0.f, 0.f};
    // x-projection (K=96; split x, split Wx)
    #pragma unroll
    for (int ks = 0; ks < 3; ++ks) {
      int kk = ks * 32 + 8 * (lane >> 4);
      bf16x8 wh = bc8(*(const uint4*)&WXAh[(size_t)colA * DPAD + kk]);
      bf16x8 wl = bc8(*(const uint4*)&WXAl[(size_t)colA * DPAD + kk]);
      bf16x8 xh = bc8(*(const uint4*)&sXh[rowl][kk]);
      bf16x8 xl = bc8(*(const uint4*)&sXl[rowl][kk]);
      accA = mfma_bf16(xh, wh, accA);
      accA = mfma_bf16(xl, wh, accA);
      accA = mfma_bf16(xh, wl, accA);
    }
    // h GEMM (K=512, split h)
    #pragma unroll
    for (int kk16 = 0; kk16 < 16; ++kk16) {
      int k = kk16 * 32 + 8 * (lane >> 4);
      bf16x8 bw = bc8(*(const uint4*)&WA[(size_t)colA * HID + k]);
      bf16x8 ah = bc8(*(const uint4*)&sHh[rowl][k]);
      bf16x8 al = bc8(*(const uint4*)&sHl[rowl][k]);
      accA = mfma_bf16(ah, bw, accA);
      accA = mfma_bf16(al, bw, accA);
    }

    // epilogue A (precise h for R*h straight from the staged LDS strip)
    #pragma unroll
    for (int r = 0; r < 4; ++r) {
      int rowm = (lane >> 4) * 4 + r;
      int grow = strip * SROWS + rowm;
      float val = fsigmoid(accA[r] + biasA);
      size_t idx = (size_t)grow * HID + colA;
      if (!isZ) {
        float hcur = bf2f(sHh[rowm][colA]) + bf2f(sHl[rowm][colA]);
        float g = val * hcur;
        u16 gh = f2bf(g);
        u16 gl = f2bf(g - bf2f(gh));
        st_u32_llc(&g_pk[idx], ((u32)gh << 16) | (u32)gl);
      } else {
        st_f32_llc(&z_buf[idx], val);
      }
    }

    // arrive(2t-1): __syncthreads drains all waves' stores (vmcnt 0) -> relaxed flag is safe
    __syncthreads();
    if (tid == 0) st_u32_llc(&gflag[part], (u32)(2 * t - 1));

    // overlap: stage xB(t) during barrier wait
    {
      const size_t xoff = (size_t)((t - 1) * NB + strip * SROWS) * DIN;
      for (int c = tid; c < SROWS * DIN; c += 256) {
        int row = c / DIN, k = c - row * DIN;
        float v = x[xoff + c] + nh[xoff + c];
        u16 hi = f2bf(v);
        sXh[row][k] = hi;
        sXl[row][k] = f2bf(v - bf2f(hi));
      }
    }
    // wait(2t-1): poll one 64B line (lanes 0..15)
    if (wave == 0) {
      const u32 target = (u32)(2 * t - 1);
      for (;;) {
        u32 a = (lane < 16) ? ld_u32_llc(&gflag[lane]) : target;
        if (__all(a >= target)) break;
      }
    }
    __syncthreads();

    // ================= PHASE B: Hh + state update =================
    // early: Z for the update (khB==0 waves)
    float zv[4];
    if (khB == 0) {
      #pragma unroll
      for (int r = 0; r < 4; ++r) {
        int brow = strip * SROWS + (lane >> 4) * 4 + r;
        zv[r] = ld_f32_llc(&z_buf[(size_t)brow * HID + colB]);
      }
    }
    // one-shot split-g strip staging
    {
      const u64* gsrc = (const u64*)g_pk;
      u64 greg[SROWS];
      #pragma unroll
      for (int i = 0; i < SROWS; ++i)
        greg[i] = ld_u64_llc(&gsrc[(size_t)(strip * SROWS + i) * 256 + tid]);
      #pragma unroll
      for (int i = 0; i < SROWS; ++i) {
        u32 v0 = (u32)greg[i], v1 = (u32)(greg[i] >> 32);
        *(u32*)&sGh[i][tid * 2] = (v0 >> 16) | (v1 & 0xFFFF0000u);
        *(u32*)&sGl[i][tid * 2] = (v0 & 0xFFFFu) | (v1 << 16);
      }
    }
    __syncthreads();

    f32x4 accB = {0.f, 0.f, 0.f, 0.f};
    if (khB == 0) {   // x-projection on k-lower waves
      #pragma unroll
      for (int ks = 0; ks < 3; ++ks) {
        int kk = ks * 32 + 8 * (lane >> 4);
        bf16x8 wh = bc8(*(const uint4*)&WXBh[(size_t)colB * DPAD + kk]);
        bf16x8 wl = bc8(*(const uint4*)&WXBl[(size_t)colB * DPAD + kk]);
        bf16x8 xh = bc8(*(const uint4*)&sXh[rowl][kk]);
        bf16x8 xl = bc8(*(const uint4*)&sXl[rowl][kk]);
        accB = mfma_bf16(xh, wh, accB);
        accB = mfma_bf16(xl, wh, accB);
        accB = mfma_bf16(xh, wl, accB);
      }
    }
    #pragma unroll
    for (int f = 0; f < 8; ++f) {
      int k = khB * 256 + f * 32 + 8 * (lane >> 4);
      bf16x8 bw = bc8(*(const uint4*)&WH[(size_t)colB * HID + k]);
      bf16x8 gh = bc8(*(const uint4*)&sGh[rowl][k]);
      bf16x8 gl = bc8(*(const uint4*)&sGl[rowl][k]);
      accB = mfma_bf16(gh, bw, accB);
      accB = mfma_bf16(gl, bw, accB);
    }
    if (khB == 1) *(f32x4*)&sC[ntB][lane][0] = accB;
    __syncthreads();

    if (khB == 0) {
      f32x4 oth = *(const f32x4*)&sC[ntB][lane][0];
      accB[0] += oth[0]; accB[1] += oth[1]; accB[2] += oth[2]; accB[3] += oth[3];
      #pragma unroll
      for (int r = 0; r < 4; ++r) {
        int brow = strip * SROWS + (lane >> 4) * 4 + r;
        float hh = ftanh(accB[r] + biasB);
        float hn = zv[r] * h_old[r] + (1.0f - zv[r]) * hh;
        h_old[r] = hn;
        u16 hi = f2bf(hn);
        u16 lo = f2bf(hn - bf2f(hi));
        st_u32_llc(&h_pk[(size_t)brow * HID + colB], ((u32)hi << 16) | (u32)lo);
        if (hs_out)
          hs_out[(size_t)((t - 1) * NB + brow) * HID + colB] = hi;
      }
    }

    // arrive(2t)
    __syncthreads();
    if (tid == 0) st_u32_llc(&gflag[part], (u32)(2 * t));

    // overlap: stage xA(t+1) during barrier wait
    if (t < TSTEPS) {
      const size_t xoff = (size_t)(t * NB + strip * SROWS) * DIN;
      for (int c = tid; c < SROWS * DIN; c += 256) {
        int row = c / DIN, k = c - row * DIN;
        float v = x[xoff + c] + nA[xoff + c];
        u16 hi = f2bf(v);
        sXh[row][k] = hi;
        sXl[row][k] = f2bf(v - bf2f(hi));
      }
    }
    // wait(2t)
    if (wave == 0) {
      const u32 target = (u32)(2 * t);
      for (;;) {
        u32 a = (lane < 16) ? ld_u32_llc(&gflag[lane]) : target;
        if (__all(a >= target)) break;
      }
    }
    __syncthreads();
  }

  // final phase C (small-ws) for t = TSTEPS
  if (do_c) {
    const int row = strip * SROWS + part;
    const int o = tid >> 3, q = tid & 7;
    const int base = row * HID + q * 64;
    float a = 0.f;
    #pragma unroll 8
    for (int k2 = 0; k2 < 64; ++k2) {
      u32 v = ld_u32_llc(&h_pk[base + k2]);
      a += (bf2f((u16)(v >> 16)) + bf2f((u16)(v & 0xFFFFu))) * Wro[(size_t)o * HID + q * 64 + k2];
    }
    __syncthreads();
    sC2[o * 8 + q] = a;
    if (tid < 8) {
      float a2 = 0.f;
      const int base2 = row * HID + tid * 64;
      #pragma unroll 8
      for (int k2 = 0; k2 < 64; ++k2) {
        u32 v = ld_u32_llc(&h_pk[base2 + k2]);
        a2 += (bf2f((u16)(v >> 16)) + bf2f((u16)(v & 0xFFFFu))) * Wro[(size_t)32 * HID + tid * 64 + k2];
      }
      sC2[32 * 8 + tid] = a2;
    }
    __syncthreads();
    if (tid < ODIM) {
      float s = bro[tid];
      #pragma unroll
      for (int q2 = 0; q2 < 8; ++q2) s += sC2[tid * 8 + q2];
      out[(size_t)((TSTEPS - 1) * NB + row) * ODIM + tid] = s;
    }
  }
}

// ---------------- output projection (big-ws path) ----------------
__global__ void __launch_bounds__(256) out_kernel(
    const u16* __restrict__ hs_out,
    const u16* __restrict__ w_rob, const float* __restrict__ b_ro,
    float* __restrict__ out)
{
  __shared__ __attribute__((aligned(16))) u16 sOh[128][72];

  const int m0   = blockIdx.x * 128;
  const int tid  = threadIdx.x;
  const int lane = tid & 63, wave = tid >> 6;

  f32x4 acc[2][3];
  for (int a = 0; a < 2; ++a) for (int b = 0; b < 3; ++b) acc[a][b] = {0.f, 0.f, 0.f, 0.f};

  for (int kc = 0; kc < 8; ++kc) {
    __syncthreads();
    #pragma unroll
    for (int i = 0; i < 4; ++i) {
      int c = tid + 256 * i; int row = c >> 3, seg = c & 7;
      *(uint4*)&sOh[row][seg * 8] =
        *(const uint4*)&hs_out[(size_t)(m0 + row) * HID + kc * 64 + seg * 8];
    }
    __syncthreads();
    #pragma unroll
    for (int ks = 0; ks < 2; ++ks) {
      int klocal = ks * 32 + 8 * (lane >> 4);
      int kglob  = kc * 64 + klocal;
      bf16x8 ah[2];
      #pragma unroll
      for (int mf = 0; mf < 2; ++mf) {
        int rowl = wave * 32 + mf * 16 + (lane & 15);
        ah[mf] = bc8(*(const uint4*)&sOh[rowl][klocal]);
      }
      #pragma unroll
      for (int nf = 0; nf < 3; ++nf) {
        int wrow = nf * 16 + (lane & 15);
        bf16x8 bw = bc8(*(const uint4*)&w_rob[(size_t)wrow * HID + kglob]);
        #pragma unroll
        for (int mf = 0; mf < 2; ++mf)
          acc[mf][nf] = mfma_bf16(ah[mf], bw, acc[mf][nf]);
      }
    }
  }
  for (int nf = 0; nf < 3; ++nf) {
    int o = nf * 16 + (lane & 15);
    if (o < ODIM) {
      float bb = b_ro[o];
      for (int mf = 0; mf < 2; ++mf)
        for (int r = 0; r < 4; ++r) {
          int R = m0 + wave * 32 + mf * 16 + (lane >> 4) * 4 + r;
          out[(size_t)R * ODIM + o] = acc[mf][nf][r] + bb;
        }
    }
  }
}

// ---------------- launcher ----------------
extern "C" void kernel_launch(void* const* d_in, const int* in_sizes, int n_in,
                              void* d_out, int out_size, void* d_ws, size_t ws_size,
                              hipStream_t stream)
{
  const float* x   = (const float*)d_in[0];
  const float* nr  = (const float*)d_in[1];
  const float* nz  = (const float*)d_in[2];
  const float* nh  = (const float*)d_in[3];
  const float* Wxr = (const float*)d_in[4];
  const float* Wxz = (const float*)d_in[5];
  const float* Wxh = (const float*)d_in[6];
  const float* Whr = (const float*)d_in[7];
  const float* bhr = (const float*)d_in[8];
  const float* Whz = (const float*)d_in[9];
  const float* bhz = (const float*)d_in[10];
  const float* Whh = (const float*)d_in[11];
  const float* bhh = (const float*)d_in[12];
  const float* Wro = (const float*)d_in[13];
  const float* bro = (const float*)d_in[14];
  float* out = (float*)d_out;

  char* ws = (char*)d_ws;
  size_t off = 0;
  auto alloc = [&](size_t bytes) -> char* {
    char* p = ws + off;
    off += (bytes + 255) & ~(size_t)255;
    return p;
  };
  u32*  h_pk  = (u32*) alloc((size_t)NB * HID * 4);       // packed hi|lo h state
  u32*  g_pk  = (u32*) alloc((size_t)NB * HID * 4);       // packed hi|lo R*h
  float* z_buf= (float*)alloc((size_t)NB * HID * 4);
  u16*  w_hb  = (u16*) alloc((size_t)3 * HID * HID * 2);
  u16*  wx_hi = (u16*) alloc((size_t)3 * HID * DPAD * 2);
  u16*  wx_lo = (u16*) alloc((size_t)3 * HID * DPAD * 2);
  u16*  w_rob = (u16*) alloc((size_t)OPAD * HID * 2);
  u32*  flags = (u32*) alloc((size_t)16 * 16 * 4);        // 16 groups x one 64B line
  size_t small_need = off;
  if (ws_size < small_need) return;   // fail numerically, never scribble

  u16* hs_out = (u16*)(ws + off);
  size_t big_need = off + (size_t)TBROWS * HID * 2 + 256;
  bool big = (ws_size >= big_need);
  if (!big) hs_out = nullptr;

  hipMemsetAsync(flags, 0, (size_t)16 * 16 * 4, stream);
  hipMemsetAsync(h_pk,  0, (size_t)NB * HID * 4, stream);   // h0 = 0

  prep_kernel<<<512, 256, 0, stream>>>(Whr, Whz, Whh, Wxr, Wxz, Wxh, Wro,
                                       w_hb, wx_hi, wx_lo, w_rob);

  recur_kernel<<<NBLK, 256, 0, stream>>>(
      x, nr, nz, nh, bhr, bhz, bhh, wx_hi, wx_lo, w_hb,
      h_pk, g_pk, z_buf, flags, hs_out, Wro, bro, out, big ? 0 : 1);

  if (big)
    out_kernel<<<TBROWS / 128, 256, 0, stream>>>(hs_out, w_rob, bro, out);
}